// Round 3
// baseline (27.110 us; speedup 1.0000x reference)
//
#include <hip/hip_runtime.h>
#include <stdint.h>

// RoI max-pool: feature_map (C,H,W) f32, proposals (N,4) f32 -> out (N,C,7,7) f32
//
// R3: LDS-free direct-gather structure. R0-R2 established that pipeline depth
// (2->4 bufs) and TLP (16->32 waves/CU) are both null -> the kernel is bound by
// per-CU shared-pipe throughput (TA segments of the staging gll16s + conflicted
// ds_read + vmcnt-coupled serial chain), which was identical across all three.
// So: delete the LDS round-trip entirely.
//
// One WAVE handles 8 channels of one proposal n. Lane l < 49 owns output bin
// (oh,ow) = (l/7, l%7). It computes its E^2 window offsets ONCE (clamped
// duplicates for smaller bins), then per channel issues E^2 independent
// global_load_dword (wave-uniform SGPR base + per-lane voffset; base bumps by
// CHW per channel) and a branch-free fmax tree. No LDS, no waitcnt asm, no
// sched barriers -- all 8*E^2 loads are independent ILP for the compiler.
// Window data is L2-resident (XCD-partitioned: blockIdx = n*8+cg -> XCD = cg%8
// owns one 32-channel slab = 400 KB) and L1-resident across the E^2 re-reads.
//
// Fallback path (degenerate/oversized region) matches the reference exactly.

constexpr int Cc = 256, Hh = 56, Ww = 56, OUTS = 7;
constexpr int CHW = Hh * Ww;        // 3136
constexpr float SCALEF = 0.0625f;   // 1/16, exact in f32
constexpr float NEGF = -3.4e+38f;
constexpr int WPB = 4;              // waves per block
constexpr int CPW = 8;              // channels per wave

template <int E>
__device__ __forceinline__ void run_channels(
    const float* __restrict__ base0,   // fm + c0*CHW (wave-uniform)
    float* __restrict__ dst0,          // out + (n*Cc + c0)*49
    int x1, int y1, int rw, int rh, int lane)
{
    const int ow = lane % OUTS;
    const int oh = lane / OUTS;
    const int ws = (ow * rw) / OUTS;
    const int ew = ((ow + 1) * rw + 6) / OUTS - ws - 1;   // extent-1 >= 0
    const int hs = (oh * rh) / OUTS;
    const int eh = ((oh + 1) * rh + 6) / OUTS - hs - 1;

    // per-lane absolute element offsets into a channel plane; clamped
    // duplicates (min) stay inside the bin -> never OOB, never wrong max
    int ofs[E * E];
#pragma unroll
    for (int kr = 0; kr < E; ++kr)
#pragma unroll
        for (int kc = 0; kc < E; ++kc)
            ofs[kr * E + kc] =
                (y1 + hs + min(kr, eh)) * Ww + (x1 + ws + min(kc, ew));

#pragma unroll
    for (int k = 0; k < CPW; ++k) {
        const float* __restrict__ b = base0 + k * CHW;  // uniform -> SGPR base
        float m = NEGF;
#pragma unroll
        for (int i = 0; i < E * E; ++i)
            m = fmaxf(m, b[ofs[i]]);
        dst0[k * (OUTS * OUTS) + lane] = m;             // contiguous 196B/wave
    }
}

__global__ __launch_bounds__(256) void roipool_kernel(
    const float* __restrict__ fm,      // (C,H,W)
    const float* __restrict__ props,   // (N,4)
    float* __restrict__ out)           // (N,C,7,7) flat
{
    const int lane = threadIdx.x & 63;
    const int wid  = __builtin_amdgcn_readfirstlane(threadIdx.x >> 6);
    const int n    = blockIdx.x >> 3;          // 8 channel-groups per n
    const int cg   = blockIdx.x & 7;           // XCD = cg -> channel slab/XCD
    const int c0   = cg * (WPB * CPW) + wid * CPW;

    // box (exact match to jnp.floor(p*0.0625) + clamps); wave-uniform -> SGPR
    const float4 p = reinterpret_cast<const float4*>(props)[n];
    const int x1 = __builtin_amdgcn_readfirstlane(max((int)floorf(p.x * SCALEF), 0));
    const int y1 = __builtin_amdgcn_readfirstlane(max((int)floorf(p.y * SCALEF), 0));
    const int x2 = __builtin_amdgcn_readfirstlane(min((int)floorf(p.z * SCALEF), Ww));
    const int y2 = __builtin_amdgcn_readfirstlane(min((int)floorf(p.w * SCALEF), Hh));
    const int rw = x2 - x1;
    const int rh = y2 - y1;

    float* dst0 = out + ((size_t)n * Cc + c0) * (OUTS * OUTS);
    const float* base0 = fm + (size_t)c0 * CHW;

    // fast path: all reads are exact window elements (clamped) -> no OOB ever;
    // rw,rh <= 20 guarantees max bin extent E <= 4
    if (rw > 0 && rh > 0 && rw <= 20 && rh <= 20) {
        // ---- wave-uniform max bin extent (scalar) ----
        int EW = 1, EH = 1;
#pragma unroll
        for (int i = 0; i < 7; ++i) {
            EW = max(EW, ((i + 1) * rw + 6) / 7 - (i * rw) / 7);
            EH = max(EH, ((i + 1) * rh + 6) / 7 - (i * rh) / 7);
        }
        const int E = max(EW, EH);      // in {1..4}

        if (lane < OUTS * OUTS) {
            if (E <= 2)      run_channels<2>(base0, dst0, x1, y1, rw, rh, lane);
            else if (E == 3) run_channels<3>(base0, dst0, x1, y1, rw, rh, lane);
            else             run_channels<4>(base0, dst0, x1, y1, rw, rh, lane);
        }
    } else {
        // ---- general fallback (not hit by this input distribution) ----
        if (lane < OUTS * OUTS) {
            const int ow = lane % OUTS;
            const int oh = lane / OUTS;
            for (int k = 0; k < CPW; ++k) {
                float m = NEGF;
                if (rw > 0 && rh > 0) {
                    const int ws = x1 + (ow * rw) / OUTS;
                    const int we = min(x1 + ((ow + 1) * rw + 6) / OUTS, Ww);
                    const int hs = y1 + (oh * rh) / OUTS;
                    const int he = min(y1 + ((oh + 1) * rh + 6) / OUTS, Hh);
                    const float* b = base0 + (size_t)k * CHW;
                    for (int h = hs; h < he; ++h)
                        for (int w = ws; w < we; ++w)
                            m = fmaxf(m, b[h * Ww + w]);
                }
                dst0[k * (OUTS * OUTS) + lane] = m;
            }
        }
    }
}

extern "C" void kernel_launch(void* const* d_in, const int* in_sizes, int n_in,
                              void* d_out, int out_size, void* d_ws, size_t ws_size,
                              hipStream_t stream)
{
    const float* fm    = (const float*)d_in[0];   // (256,56,56)
    const float* props = (const float*)d_in[1];   // (128,4)
    float* out = (float*)d_out;                   // (128,256,7,7)

    const int N = in_sizes[1] / 4;                 // 128
    const int blocks = N * (Cc / (WPB * CPW));     // 1024 blocks x 256 threads
    roipool_kernel<<<blocks, 256, 0, stream>>>(fm, props, out);
}

// Round 4
// 19.823 us; speedup vs baseline: 1.3676x; 1.3676x over previous
//
#include <hip/hip_runtime.h>
#include <stdint.h>

// RoI max-pool: feature_map (C,H,W) f32, proposals (N,4) f32 -> out (N,C,7,7) f32
//
// R4: plane-resident structure. Evidence so far:
//   R0->R1 pipeline depth 2->4: null. R1->R2 TLP 16->32 waves/CU: null.
//   R2->R3 LDS-staging -> direct per-lane gather: 13 -> 27 us (2x WORSE), with
//   ~4x the TA/L2 request segments. Model: time ~ per-CU memory-request
//   segment count x ~4cyc, invariant across R0-R2 (identical staging), 2x in
//   R3. So attack the request count itself.
//
// One BLOCK owns one channel plane: stage all 3136 floats (12.25 KB) into LDS
// with 13 global_load_lds (vs 256 window-stages in R0-R2), one __syncthreads,
// then 8 waves each compute 8 proposals' 7x7 bins straight from LDS.
// Per-channel request segments: ~200 fetch + ~512 store  (was ~4600) -> ~5x
// fewer TA segments per CU. No vmcnt asm, no sched barriers. Each plane is
// fetched by exactly 2 blocks mapped to the SAME XCD (blockIdx%8 == c%8), so
// HBM fetch ~= unique bytes.
//
// All proposal geometry (incl. arbitrary rw,rh) is served from the LDS plane;
// degenerate boxes (rw<=0||rh<=0) produce NEG everywhere, matching reference.

constexpr int Cc = 256, Hh = 56, Ww = 56, OUTS = 7;
constexpr int CHW   = Hh * Ww;     // 3136 floats per plane
constexpr int QUADS = CHW / 4;     // 784 float4s
constexpr float SCALEF = 0.0625f;  // 1/16, exact in f32
constexpr float NEGF = -3.4e+38f;
constexpr int TPB = 512;           // 8 waves per block
constexpr int NPW = 8;             // proposals per wave (8 waves x 8 = 64 per block)

__device__ __forceinline__ void gll16(const float* g, float* l) {
    __builtin_amdgcn_global_load_lds(
        (const __attribute__((address_space(1))) uint32_t*)g,
        (__attribute__((address_space(3))) uint32_t*)l, 16, 0, 0);
}

template <int E>
__device__ __forceinline__ float binmax_lds(const float* __restrict__ plane,
                                            int basef, int eh, int ew)
{
    // basef = (y1+hs)*W + x1+ws; clamped duplicates stay inside the bin
    float m = NEGF;
#pragma unroll
    for (int kr = 0; kr < E; ++kr) {
        const int ro = min(kr, eh) * Ww;
#pragma unroll
        for (int kc = 0; kc < E; ++kc)
            m = fmaxf(m, plane[basef + ro + min(kc, ew)]);
    }
    return m;
}

__global__ __launch_bounds__(TPB) void roipool_kernel(
    const float* __restrict__ fm,      // (C,H,W)
    const float* __restrict__ props,   // (N,4)
    float* __restrict__ out)           // (N,C,7,7) flat
{
    // 3328 floats = 13 KB: 13th gll16 (lanes 16..63 clamped) spills into
    // plane[3136..3327] junk that is never read. 2 blocks/CU -> 26 KB.
    __shared__ float plane[3328];

    const int lane = threadIdx.x & 63;
    const int wid  = __builtin_amdgcn_readfirstlane(threadIdx.x >> 6);
    const int c     = blockIdx.x & (Cc - 1);          // channel (XCD = c%8)
    const int nbase = (blockIdx.x >> 8) * 64 + wid * NPW;

    const float* cbase = fm + (size_t)c * CHW;

    // ---- stage the whole plane: 13 x gll16 spread over 8 waves ----
    // dest base is wave-uniform (HW adds lane*16B); source quad clamped so the
    // tail instruction never reads past the end of fm (c = 255).
    for (int i = wid; i <= 12; i += 8) {
        const int q = min(i * 64 + lane, QUADS - 1);
        gll16(cbase + q * 4, &plane[i * 256]);
    }
    __syncthreads();          // drains vmcnt, publishes plane to all waves

    // lanes >= 49 compute a harmless duplicate bin (oh clamped); store guarded
    const int ow = lane % OUTS;
    const int oh = min(lane / OUTS, OUTS - 1);

    for (int j = 0; j < NPW; ++j) {
        const int n = nbase + j;

        // box (exact match to jnp.floor(p*0.0625) + clamps); uniform -> SGPR
        const float4 p = reinterpret_cast<const float4*>(props)[n];
        const int x1 = __builtin_amdgcn_readfirstlane(max((int)floorf(p.x * SCALEF), 0));
        const int y1 = __builtin_amdgcn_readfirstlane(max((int)floorf(p.y * SCALEF), 0));
        const int x2 = __builtin_amdgcn_readfirstlane(min((int)floorf(p.z * SCALEF), Ww));
        const int y2 = __builtin_amdgcn_readfirstlane(min((int)floorf(p.w * SCALEF), Hh));
        const int rw = x2 - x1;
        const int rh = y2 - y1;

        float m = NEGF;
        if (rw > 0 && rh > 0) {
            // wave-uniform max bin extent (pure SALU, overlaps VALU/LDS)
            int EW = 1, EH = 1;
#pragma unroll
            for (int i = 0; i < 7; ++i) {
                EW = max(EW, ((i + 1) * rw + 6) / 7 - (i * rw) / 7);
                EH = max(EH, ((i + 1) * rh + 6) / 7 - (i * rh) / 7);
            }
            const int E = max(EW, EH);   // <=4 whenever rw,rh <= 28

            const int ws = (ow * rw) / OUTS;
            const int ew = ((ow + 1) * rw + 6) / OUTS - ws - 1;  // extent-1 >= 0
            const int hs = (oh * rh) / OUTS;
            const int eh = ((oh + 1) * rh + 6) / OUTS - hs - 1;
            const int basef = (y1 + hs) * Ww + x1 + ws;          // in-plane

            if (E <= 2)      m = binmax_lds<2>(plane, basef, eh, ew);
            else if (E == 3) m = binmax_lds<3>(plane, basef, eh, ew);
            else if (E == 4) m = binmax_lds<4>(plane, basef, eh, ew);
            else {
                // huge box (not in this distro): dynamic loops, still from LDS
                const int he = ((oh + 1) * rh + 6) / OUTS;
                const int we = ((ow + 1) * rw + 6) / OUTS;
                for (int h = hs; h < he; ++h)
                    for (int w = ws; w < we; ++w)
                        m = fmaxf(m, plane[(y1 + h) * Ww + x1 + w]);
            }
        }
        if (lane < OUTS * OUTS)
            out[((size_t)n * Cc + c) * (OUTS * OUTS) + lane] = m;
    }
}

extern "C" void kernel_launch(void* const* d_in, const int* in_sizes, int n_in,
                              void* d_out, int out_size, void* d_ws, size_t ws_size,
                              hipStream_t stream)
{
    const float* fm    = (const float*)d_in[0];   // (256,56,56)
    const float* props = (const float*)d_in[1];   // (128,4)
    float* out = (float*)d_out;                   // (128,256,7,7)

    const int N = in_sizes[1] / 4;                 // 128
    const int blocks = Cc * (N / 64);              // 512 blocks x 512 threads
    roipool_kernel<<<blocks, TPB, 0, stream>>>(fm, props, out);
}

// Round 5
// 13.348 us; speedup vs baseline: 2.0311x; 1.4852x over previous
//
#include <hip/hip_runtime.h>
#include <stdint.h>

// RoI max-pool: feature_map (C,H,W) f32, proposals (N,4) f32 -> out (N,C,7,7) f32
//
// R5 = R1 (best measured, 12.97us) + asymmetric (EH,EW) bin dispatch.
// Evidence R0-R4: pipeline depth null, TLP null, gather 2x worse (request
// explosion), plane-LDS 1.5x worse (serial decode). The invariant across all
// five is the compute CORE: E^2 LDS reads + E^2 fmax per bin with
// E = max(EW,EH). This round shrinks the core ~33% by dispatching on
// (EH,EW) separately: E[EH*EW] ~ 5.5 vs E[max^2] ~ 8.2 for this box
// distribution. Staging/waits byte-identical to R1.
//
// One WAVE handles 8 channels of one proposal n.
//   - staging: global_load_lds width=16 (2 per channel), linear LDS dest,
//     row pitch 24 floats; tail lanes clamp SOURCE row to rh-1.
//   - pipeline: NBUF=4; prologue stages ch 0..3; iteration k computes ch k,
//     stores, restages buf[k&3] for ch k+4. Counted vmcnt {6,7,8,9,9,7,5,3}.
//   - compute: extents wave-uniform (SGPR); 16-way uniform switch into
//     binmax2<EH,EW>, per-lane clamped (duplicate reads stay inside bin).
// Fallback path (degenerate/oversized region) matches the reference exactly.

constexpr int Cc = 256, Hh = 56, Ww = 56, OUTS = 7;
constexpr int CHW = Hh * Ww;        // 3136
constexpr float SCALEF = 0.0625f;   // 1/16, exact in f32
constexpr float NEGF = -3.4e+38f;
constexpr int RH     = 20;          // max staged rows (this distro: rh<=19)
constexpr int RWQ    = 6;           // float4s per row (24-float window)
constexpr int PITCHF = 24;          // floats per LDS row (= RWQ*4, linear lane map)
constexpr int BUFF   = 512;         // floats per channel buffer (2 gll = 128x16B)
constexpr int WPB    = 4;           // waves per block
constexpr int CPW    = 8;           // channels per wave
constexpr int NBUF   = 4;           // pipeline depth (channel buffers per wave)

__device__ __forceinline__ void gll16(const float* g, float* l) {
    __builtin_amdgcn_global_load_lds(
        (const __attribute__((address_space(1))) uint32_t*)g,
        (__attribute__((address_space(3))) uint32_t*)l, 16, 0, 0);
}

template <int EHt, int EWt>
__device__ __forceinline__ float binmax2(const float* __restrict__ base,
                                         int eh, int ew)
{
    // base = &buf[hs*PITCHF + wofs + ws]; clamped duplicates stay inside bin
    float m = NEGF;
#pragma unroll
    for (int kr = 0; kr < EHt; ++kr) {
        const int ro = min(kr, eh) * PITCHF;
#pragma unroll
        for (int kc = 0; kc < EWt; ++kc)
            m = fmaxf(m, base[ro + min(kc, ew)]);
    }
    return m;
}

__device__ __forceinline__ float binmax_dispatch(const float* __restrict__ bb,
                                                 int eh, int ew, int key)
{
    // key = (EH-1)*4 + (EW-1), wave-uniform in [0,15]
    switch (key) {
        case  0: return binmax2<1,1>(bb, eh, ew);
        case  1: return binmax2<1,2>(bb, eh, ew);
        case  2: return binmax2<1,3>(bb, eh, ew);
        case  3: return binmax2<1,4>(bb, eh, ew);
        case  4: return binmax2<2,1>(bb, eh, ew);
        case  5: return binmax2<2,2>(bb, eh, ew);
        case  6: return binmax2<2,3>(bb, eh, ew);
        case  7: return binmax2<2,4>(bb, eh, ew);
        case  8: return binmax2<3,1>(bb, eh, ew);
        case  9: return binmax2<3,2>(bb, eh, ew);
        case 10: return binmax2<3,3>(bb, eh, ew);
        case 11: return binmax2<3,4>(bb, eh, ew);
        case 12: return binmax2<4,1>(bb, eh, ew);
        case 13: return binmax2<4,2>(bb, eh, ew);
        case 14: return binmax2<4,3>(bb, eh, ew);
        default: return binmax2<4,4>(bb, eh, ew);
    }
}

__global__ __launch_bounds__(256) void roipool_kernel(
    const float* __restrict__ fm,      // (C,H,W)
    const float* __restrict__ props,   // (N,4)
    float* __restrict__ out)           // (N,C,7,7) flat
{
    __shared__ float lds[WPB][NBUF][BUFF];     // 32 KB/block

    const int lane = threadIdx.x & 63;
    const int wid  = __builtin_amdgcn_readfirstlane(threadIdx.x >> 6);
    const int n    = blockIdx.x >> 3;          // 8 channel-groups per n
    const int cg   = blockIdx.x & 7;
    const int c0   = cg * (WPB * CPW) + wid * CPW;

    // box (exact match to jnp.floor(p*0.0625) + clamps); wave-uniform -> SGPR
    const float4 p = reinterpret_cast<const float4*>(props)[n];
    const int x1 = __builtin_amdgcn_readfirstlane(max((int)floorf(p.x * SCALEF), 0));
    const int y1 = __builtin_amdgcn_readfirstlane(max((int)floorf(p.y * SCALEF), 0));
    const int x2 = __builtin_amdgcn_readfirstlane(min((int)floorf(p.z * SCALEF), Ww));
    const int y2 = __builtin_amdgcn_readfirstlane(min((int)floorf(p.w * SCALEF), Hh));
    const int rw = x2 - x1;
    const int rh = y2 - y1;

    float* dst0 = out + ((size_t)n * Cc + c0) * (OUTS * OUTS);
    const float* base0 = fm + (size_t)c0 * CHW;
    const int x1a = x1 & ~3;            // aligned window start

    // fast path: region fits 20x24 window; overread never passes end of fm
    if (rw > 0 && rh > 0 && rw <= 20 && rh <= RH &&
        (y1 + rh < Hh || x1a + RWQ * 4 <= Ww)) {

        // ---- wave-uniform max bin extents (scalar), kept SEPARATE ----
        int EW = 1, EH = 1;
#pragma unroll
        for (int i = 0; i < 7; ++i) {
            EW = max(EW, ((i + 1) * rw + 6) / 7 - (i * rw) / 7);
            EH = max(EH, ((i + 1) * rh + 6) / 7 - (i * rh) / 7);
        }
        const int key = __builtin_amdgcn_readfirstlane((EH - 1) * 4 + (EW - 1));

        // ---- per-lane staging source offsets (row-clamped: count-stable) ----
        const int r0 = lane / RWQ,        q0 = lane - r0 * RWQ;
        const int r1 = (lane + 64) / RWQ, q1 = (lane + 64) - r1 * RWQ;
        const int go0 = min(r0, rh - 1) * Ww + q0 * 4;
        const int go1 = min(r1, rh - 1) * Ww + q1 * 4;
        const float* src0 = base0 + y1 * Ww + x1a;    // 16B-aligned

        // ---- per-lane bin coords ----
        const int ow = lane % OUTS;
        const int oh = lane / OUTS;
        const int ws = (ow * rw) / OUTS;
        const int ew = ((ow + 1) * rw + 6) / OUTS - ws - 1;   // extent-1 >= 0
        const int hs = (oh * rh) / OUTS;
        const int eh = ((oh + 1) * rh + 6) / OUTS - hs - 1;
        const int bofs = hs * PITCHF + (x1 - x1a) + ws;

        // ---- prologue: stage channels 0..3 (8 loads in flight) ----
#pragma unroll
        for (int k = 0; k < NBUF; ++k) {
            const float* s = src0 + k * CHW;
            float* b = &lds[wid][k][0];
            gll16(s + go0, b);
            gll16(s + go1, b + 256);
        }
        __builtin_amdgcn_sched_barrier(0);

#pragma unroll
        for (int k = 0; k < CPW; ++k) {
            // counted waits: exactly drain channel k's 2 loads.
            // FIFO: L0L0 L1L1 L2L2 L3L3 | S0 L4L4 | S1 L5L5 | S2 L6L6 |
            //       S3 L7L7 | S4 | S5 | S6 | S7
            if      (k == 0) asm volatile("s_waitcnt vmcnt(6)" ::: "memory");
            else if (k == 1) asm volatile("s_waitcnt vmcnt(7)" ::: "memory");
            else if (k == 2) asm volatile("s_waitcnt vmcnt(8)" ::: "memory");
            else if (k == 3) asm volatile("s_waitcnt vmcnt(9)" ::: "memory");
            else if (k == 4) asm volatile("s_waitcnt vmcnt(9)" ::: "memory");
            else if (k == 5) asm volatile("s_waitcnt vmcnt(7)" ::: "memory");
            else if (k == 6) asm volatile("s_waitcnt vmcnt(5)" ::: "memory");
            else             asm volatile("s_waitcnt vmcnt(3)" ::: "memory");
            __builtin_amdgcn_sched_barrier(0);

            if (lane < OUTS * OUTS) {
                const float* bb = &lds[wid][k & (NBUF - 1)][0] + bofs;
                dst0[k * (OUTS * OUTS) + lane] = binmax_dispatch(bb, eh, ew, key);
            }
            // pin: restage must not be hoisted above the compute that reads
            // this buffer (ch k's ds_reads complete before the store issues;
            // gll16's LDS write lands >= 1 memory latency after issue)
            __builtin_amdgcn_sched_barrier(0);

            if (k + NBUF < CPW) {                    // restage buf[k&3] for k+4
                const float* s = src0 + (k + NBUF) * CHW;
                float* b = &lds[wid][k & (NBUF - 1)][0];
                gll16(s + go0, b);
                gll16(s + go1, b + 256);
                __builtin_amdgcn_sched_barrier(0);
            }
        }
    } else {
        // ---- general fallback (not hit by this input distribution) ----
        if (lane < OUTS * OUTS) {
            const int ow = lane % OUTS;
            const int oh = lane / OUTS;
            for (int k = 0; k < CPW; ++k) {
                float m = NEGF;
                if (rw > 0 && rh > 0) {
                    const int ws = x1 + (ow * rw) / OUTS;
                    const int we = min(x1 + ((ow + 1) * rw + 6) / OUTS, Ww);
                    const int hs = y1 + (oh * rh) / OUTS;
                    const int he = min(y1 + ((oh + 1) * rh + 6) / OUTS, Hh);
                    const float* b = base0 + (size_t)k * CHW;
                    for (int h = hs; h < he; ++h)
                        for (int w = ws; w < we; ++w)
                            m = fmaxf(m, b[h * Ww + w]);
                }
                dst0[k * (OUTS * OUTS) + lane] = m;
            }
        }
    }
}

extern "C" void kernel_launch(void* const* d_in, const int* in_sizes, int n_in,
                              void* d_out, int out_size, void* d_ws, size_t ws_size,
                              hipStream_t stream)
{
    const float* fm    = (const float*)d_in[0];   // (256,56,56)
    const float* props = (const float*)d_in[1];   // (128,4)
    float* out = (float*)d_out;                   // (128,256,7,7)

    const int N = in_sizes[1] / 4;                 // 128
    const int blocks = N * (Cc / (WPB * CPW));     // 1024 blocks x 256 threads
    roipool_kernel<<<blocks, 256, 0, stream>>>(fm, props, out);
}